// Round 7
// baseline (104.551 us; speedup 1.0000x reference)
//
#include <hip/hip_runtime.h>
#include <hip/hip_bf16.h>

// Conv2.5D disparity-masked conv as implicit GEMM on bf16 MFMA, v7.
// D[o,l] = sum_{p,t,c} W_t[o,c,p] * x[c, l shifted by p] * m_t[p,l]
// v7: 2-row x 64-px blocks (grid 1024). Wave = 32 outs x (32 cols x 2 rows),
// 2 accumulators sharing each A-fragment (A-traffic/MFMA halved vs v6);
// halo staging redundancy 3.1 -> 2.06 staged-px per out-px. Exact all-zero
// fragment skip (bit-exact) retained.

#define IN_C 32
#define OUT_C 64
#define IMG 256
#define HW 66           // halo width: 64 + 2
#define HR 4            // halo rows: 2 + 2

typedef __bf16 bf16x8 __attribute__((ext_vector_type(8)));
typedef float f32x16 __attribute__((ext_vector_type(16)));
union B128 { uint4 i4; bf16x8 v; };

// ---- prep: weights into A-fragment order (proven rounds 2-6) ---------------
// wA[q][ot][lane] (uint4 each), q = p*6 + t*2 + chalf.
// A[m = ot*32 + (lane&31)][k_in = (lane>>5)*8 + j], c = chalf*16 + k_in.
__global__ void build_wA(const float* __restrict__ w0,
                         const float* __restrict__ w1,
                         const float* __restrict__ w2,
                         __hip_bfloat16* __restrict__ wA) {
    int tid = blockIdx.x * 256 + threadIdx.x;      // q*128 + ot*64 + lane
    if (tid >= 54 * 128) return;
    int lane  = tid & 63;
    int ot    = (tid >> 6) & 1;
    int q     = tid >> 7;
    int p     = q / 6;
    int rm    = q - p * 6;
    int t     = rm >> 1;
    int chalf = rm & 1;
    int o     = ot * 32 + (lane & 31);
    int cbase = chalf * 16 + (lane >> 5) * 8;
    const float* w = (t == 0) ? w0 : (t == 1) ? w1 : w2;
    __hip_bfloat16* dst = wA + (size_t)tid * 8;
    #pragma unroll
    for (int j = 0; j < 8; ++j) {
        float v = w[(o * IN_C + cbase + j) * 9 + p];
        dst[j] = __float2bfloat16(v);
    }
}

// ---- main kernel -----------------------------------------------------------
// Block = 2 rows x 64 px. 2n x 128 rowpairs x 4 colq = 1024 blocks.
// Wave w: ot = w&1 (32 outs), ph = w>>1 (cols [ph*32, ph*32+32), both rows).
__global__ __launch_bounds__(256, 4) void conv25d_mfma7(
    const float* __restrict__ x, const float* __restrict__ disp,
    const float* __restrict__ fx, const float* __restrict__ baseline,
    const uint4* __restrict__ wA, float* __restrict__ out) {

    // x halo strip as 4 k-slot planes x 4 halo rows: sx[(s*HR + r)*HW + cc2].
    // plane s holds channels [s*8, s*8+8) of pixel (row0+r-1, colbase+cc2-1).
    __shared__ __align__(16) uint4 sx[4 * HR * HW];   // 16896 B
    __shared__ float sdisp[HR * HW];                  // 1056 B

    const int tid = threadIdx.x;
    const int bid = blockIdx.x;
    const int n       = bid >> 9;
    const int rem     = bid & 511;
    const int row0    = (rem >> 2) * 2;
    const int colbase = (rem & 3) << 6;               // 0/64/128/192

    // stage disp halo + x halo strip (fp32 -> bf16 planes), 264 positions
    for (int idx = tid; idx < HR * HW; idx += 256) {
        int r = idx / HW, cc2 = idx - r * HW;
        int gr = row0 + r - 1, gc = colbase + cc2 - 1;
        bool ok = (gr >= 0) && (gr < IMG) && (gc >= 0) && (gc < IMG);
        float dv = 0.f;
        unsigned w[16];
        #pragma unroll
        for (int j = 0; j < 16; ++j) w[j] = 0u;
        if (ok) {
            dv = disp[(n * IMG + gr) * IMG + gc];
            const float* src = x + ((size_t)(n * IN_C) * IMG + gr) * IMG + gc;
            #pragma unroll
            for (int j = 0; j < 16; ++j) {
                float a = src[(size_t)(2 * j) * (IMG * IMG)];
                float b = src[(size_t)(2 * j + 1) * (IMG * IMG)];
                __hip_bfloat162 h2 = __float22bfloat162_rn(make_float2(a, b));
                w[j] = *reinterpret_cast<unsigned*>(&h2);
            }
        }
        sdisp[idx] = dv;
        sx[(0 * HR + r) * HW + cc2] = make_uint4(w[0],  w[1],  w[2],  w[3]);
        sx[(1 * HR + r) * HW + cc2] = make_uint4(w[4],  w[5],  w[6],  w[7]);
        sx[(2 * HR + r) * HW + cc2] = make_uint4(w[8],  w[9],  w[10], w[11]);
        sx[(3 * HR + r) * HW + cc2] = make_uint4(w[12], w[13], w[14], w[15]);
    }
    __syncthreads();   // the only barrier

    const int lane = tid & 63;
    const int wv   = tid >> 6;
    const int ot   = wv & 1;          // out-half: outs [ot*32, ot*32+32)
    const int ph   = wv >> 1;         // col-half: cols [ph*32, ph*32+32)
    const int l31  = lane & 31;
    const int half = lane >> 5;
    const float fxv = fx[n];
    const float bfx = baseline[n] * fxv;

    const int l = ph * 32 + l31;      // within-block col

    // 27 mask bits per owned pixel, for each of the 2 rows
    unsigned mbits[2];
    #pragma unroll
    for (int rr = 0; rr < 2; ++rr) {
        float dc = sdisp[(rr + 1) * HW + l + 1];
        float cd = bfx / fminf(fmaxf(dc, 0.01f), 256.f);
        float g  = 16.f * cd / fxv;
        float h  = g * 0.5f;
        unsigned bits = 0u;
        #pragma unroll
        for (int p = 0; p < 9; ++p) {
            int pi = p / 3, pj = p - pi * 3;
            float dval = sdisp[(rr + pi) * HW + l + pj];
            bool validp = (dval != 0.f) && (dc != 0.f);
            float dmv   = validp ? dval : 0.f;
            float depth = bfx / fminf(fmaxf(dmv, 0.01f), 256.f);
            bool m0 = fabsf(depth - (cd + g)) <= h;
            bool m1 = (fabsf(depth - cd) <= h) || (!validp);
            bool m2 = fabsf(depth - (cd - g)) <= h;
            bits |= ((m0 ? 1u : 0u) << (3 * p))
                  | ((m1 ? 1u : 0u) << (3 * p + 1))
                  | ((m2 ? 1u : 0u) << (3 * p + 2));
        }
        mbits[rr] = bits;
    }

    // wave-uniform OR of mask bits -> SGPRs (exact skip tests)
    unsigned smu[2];
    #pragma unroll
    for (int rr = 0; rr < 2; ++rr) {
        unsigned b = mbits[rr];
        #pragma unroll
        for (int off = 32; off >= 1; off >>= 1)
            b |= (unsigned)__shfl_xor((int)b, off, 64);
        smu[rr] = __builtin_amdgcn_readfirstlane(b);
    }
    const unsigned stap = smu[0] | smu[1];

    f32x16 acc[2];     // [rr]
    #pragma unroll
    for (int rr = 0; rr < 2; ++rr)
        #pragma unroll
        for (int r = 0; r < 16; ++r) acc[rr][r] = 0.f;

    #pragma unroll
    for (int p = 0; p < 9; ++p) {
        const int pi = p / 3, pj = p - pi * 3;
        if (!((stap >> (3 * p)) & 7u)) continue;   // whole tap dead (scalar)

        // raw bf16 x fragments per row (lane-contiguous b128 LDS reads)
        B128 xr[2][2];   // [rr][chalf]; plane s = chalf*2 + half
        const int cc2 = l + pj;
        #pragma unroll
        for (int rr = 0; rr < 2; ++rr) {
            if ((smu[rr] >> (3 * p)) & 7u) {
                #pragma unroll
                for (int ch = 0; ch < 2; ++ch)
                    xr[rr][ch].i4 =
                        sx[((ch * 2 + half) * HR + (rr + pi)) * HW + cc2];
            }
        }

        #pragma unroll
        for (int t = 0; t < 3; ++t) {
            if ((stap >> (3 * p + t)) & 1u) {      // scalar branch
                B128 a0, a1;                       // shared by both rows
                a0.i4 = wA[(p * 6 + t * 2 + 0) * 128 + ot * 64 + lane];
                a1.i4 = wA[(p * 6 + t * 2 + 1) * 128 + ot * 64 + lane];
                #pragma unroll
                for (int rr = 0; rr < 2; ++rr) {
                    if ((smu[rr] >> (3 * p + t)) & 1u) {
                        unsigned m = 0u - ((mbits[rr] >> (3 * p + t)) & 1u);
                        B128 b0, b1;
                        b0.i4 = make_uint4(xr[rr][0].i4.x & m, xr[rr][0].i4.y & m,
                                           xr[rr][0].i4.z & m, xr[rr][0].i4.w & m);
                        b1.i4 = make_uint4(xr[rr][1].i4.x & m, xr[rr][1].i4.y & m,
                                           xr[rr][1].i4.z & m, xr[rr][1].i4.w & m);
                        acc[rr] = __builtin_amdgcn_mfma_f32_32x32x16_bf16(
                                      a0.v, b0.v, acc[rr], 0, 0, 0);
                        acc[rr] = __builtin_amdgcn_mfma_f32_32x32x16_bf16(
                                      a1.v, b1.v, acc[rr], 0, 0, 0);
                    }
                }
            }
        }
    }

    // epilogue: D[o_local = (reg&3)+8*(reg>>2)+4*half][col = l31] (proven)
    #pragma unroll
    for (int rr = 0; rr < 2; ++rr) {
        float* ob = out + (size_t)(n * OUT_C) * (IMG * IMG)
                  + (size_t)(row0 + rr) * IMG + colbase + ph * 32 + l31;
        #pragma unroll
        for (int reg = 0; reg < 16; ++reg) {
            int ol = (reg & 3) + 8 * (reg >> 2) + 4 * half + ot * 32;
            ob[(size_t)ol * (IMG * IMG)] = acc[rr][reg];
        }
    }
}

extern "C" void kernel_launch(void* const* d_in, const int* in_sizes, int n_in,
                              void* d_out, int out_size, void* d_ws, size_t ws_size,
                              hipStream_t stream) {
    const float* x        = (const float*)d_in[0];
    const float* disp     = (const float*)d_in[1];
    const float* fx       = (const float*)d_in[2];
    const float* baseline = (const float*)d_in[3];
    const float* w0       = (const float*)d_in[4];
    const float* w1       = (const float*)d_in[5];
    const float* w2       = (const float*)d_in[6];
    float* out            = (float*)d_out;

    __hip_bfloat16* wA = (__hip_bfloat16*)d_ws;   // 54*128*16 = 110592 B

    build_wA<<<27, 256, 0, stream>>>(w0, w1, w2, wA);
    conv25d_mfma7<<<1024, 256, 0, stream>>>(x, disp, fx, baseline,
                                            (const uint4*)wA, out);
}

// Round 8
// 102.217 us; speedup vs baseline: 1.0228x; 1.0228x over previous
//
#include <hip/hip_runtime.h>
#include <hip/hip_bf16.h>

// Conv2.5D disparity-masked conv as implicit GEMM on bf16 MFMA, v6 (final).
// D[o,l] = sum_{p,t,c} W_t[o,c,p] * x[c, l shifted by p] * m_t[p,l]
// v6: 64-px blocks, grid 2048, LDS 13.5 KB -> 8 blocks/CU (32 waves/CU, HW max)
// for staging/compute overlap. Wave = 32 outs x 32 px. Exact all-zero-fragment
// skip (bit-exact). Best measured: 101.7 us total; main kernel is at its
// HBM/LLC stream floor (~67 MB traffic), remainder is harness-fixed resets.

#define IN_C 32
#define OUT_C 64
#define IMG 256
#define HW 66           // halo width: 64 + 2

typedef __bf16 bf16x8 __attribute__((ext_vector_type(8)));
typedef float f32x16 __attribute__((ext_vector_type(16)));
union B128 { uint4 i4; bf16x8 v; };

// ---- prep: weights into A-fragment order (proven rounds 2-7) ---------------
// wA[q][ot][lane] (uint4 each), q = p*6 + t*2 + chalf.
// A[m = ot*32 + (lane&31)][k_in = (lane>>5)*8 + j], c = chalf*16 + k_in.
__global__ void build_wA(const float* __restrict__ w0,
                         const float* __restrict__ w1,
                         const float* __restrict__ w2,
                         __hip_bfloat16* __restrict__ wA) {
    int tid = blockIdx.x * 256 + threadIdx.x;      // q*128 + ot*64 + lane
    if (tid >= 54 * 128) return;
    int lane  = tid & 63;
    int ot    = (tid >> 6) & 1;
    int q     = tid >> 7;
    int p     = q / 6;
    int rm    = q - p * 6;
    int t     = rm >> 1;
    int chalf = rm & 1;
    int o     = ot * 32 + (lane & 31);
    int cbase = chalf * 16 + (lane >> 5) * 8;
    const float* w = (t == 0) ? w0 : (t == 1) ? w1 : w2;
    __hip_bfloat16* dst = wA + (size_t)tid * 8;
    #pragma unroll
    for (int j = 0; j < 8; ++j) {
        float v = w[(o * IN_C + cbase + j) * 9 + p];
        dst[j] = __float2bfloat16(v);
    }
}

// ---- main kernel -----------------------------------------------------------
// Block = 64 px of one row. 2n x 256row x 4colq = 2048 blocks (8/CU).
// Wave w: ot = w&1 (32 outs), ph = w>>1 (32 px).
__global__ __launch_bounds__(256, 8) void conv25d_mfma6(
    const float* __restrict__ x, const float* __restrict__ disp,
    const float* __restrict__ fx, const float* __restrict__ baseline,
    const uint4* __restrict__ wA, float* __restrict__ out) {

    // x halo strip as 4 k-slot planes: sx[(s*3 + r')*HW + cc2], 16 B entries.
    // plane s holds channels [s*8, s*8+8) of pixel (row+r'-1, colbase+cc2-1).
    __shared__ __align__(16) uint4 sx[12 * HW];    // 12672 B
    __shared__ float sdisp[3 * HW];                // 792 B

    const int tid = threadIdx.x;
    const int bid = blockIdx.x;
    const int n       = bid >> 10;
    const int rem     = bid & 1023;
    const int row     = rem >> 2;
    const int colbase = (rem & 3) << 6;            // 0/64/128/192

    // stage disp halo + x halo strip (fp32 -> bf16 planes), 198 idx < 256
    if (tid < 3 * HW) {
        int r = tid / HW, cc2 = tid - r * HW;
        int gr = row + r - 1, gc = colbase + cc2 - 1;
        bool ok = (gr >= 0) && (gr < IMG) && (gc >= 0) && (gc < IMG);
        float dv = 0.f;
        unsigned w[16];
        #pragma unroll
        for (int j = 0; j < 16; ++j) w[j] = 0u;
        if (ok) {
            dv = disp[(n * IMG + gr) * IMG + gc];
            const float* src = x + ((size_t)(n * IN_C) * IMG + gr) * IMG + gc;
            #pragma unroll
            for (int j = 0; j < 16; ++j) {
                float a = src[(size_t)(2 * j) * (IMG * IMG)];
                float b = src[(size_t)(2 * j + 1) * (IMG * IMG)];
                __hip_bfloat162 h2 = __float22bfloat162_rn(make_float2(a, b));
                w[j] = *reinterpret_cast<unsigned*>(&h2);
            }
        }
        sdisp[tid] = dv;
        sx[(0 * 3 + r) * HW + cc2] = make_uint4(w[0],  w[1],  w[2],  w[3]);
        sx[(1 * 3 + r) * HW + cc2] = make_uint4(w[4],  w[5],  w[6],  w[7]);
        sx[(2 * 3 + r) * HW + cc2] = make_uint4(w[8],  w[9],  w[10], w[11]);
        sx[(3 * 3 + r) * HW + cc2] = make_uint4(w[12], w[13], w[14], w[15]);
    }
    __syncthreads();   // the only barrier

    const int lane = tid & 63;
    const int wv   = tid >> 6;
    const int ot   = wv & 1;          // out-half: outs [ot*32, ot*32+32)
    const int ph   = wv >> 1;         // pixel-half: cols [ph*32, ph*32+32)
    const int l31  = lane & 31;
    const int half = lane >> 5;
    const float fxv = fx[n];
    const float bfx = baseline[n] * fxv;

    // 27 mask bits for this wave's 32 pixels
    const int l = ph * 32 + l31;      // within-block col
    unsigned mbits;
    {
        float dc = sdisp[HW + l + 1];
        float cd = bfx / fminf(fmaxf(dc, 0.01f), 256.f);
        float g  = 16.f * cd / fxv;
        float h  = g * 0.5f;
        unsigned bits = 0u;
        #pragma unroll
        for (int p = 0; p < 9; ++p) {
            int pi = p / 3, pj = p - pi * 3;
            float dval = sdisp[pi * HW + l + pj];
            bool validp = (dval != 0.f) && (dc != 0.f);
            float dmv   = validp ? dval : 0.f;
            float depth = bfx / fminf(fmaxf(dmv, 0.01f), 256.f);
            bool m0 = fabsf(depth - (cd + g)) <= h;
            bool m1 = (fabsf(depth - cd) <= h) || (!validp);
            bool m2 = fabsf(depth - (cd - g)) <= h;
            bits |= ((m0 ? 1u : 0u) << (3 * p))
                  | ((m1 ? 1u : 0u) << (3 * p + 1))
                  | ((m2 ? 1u : 0u) << (3 * p + 2));
        }
        mbits = bits;
    }

    // wave-uniform OR of mask bits -> SGPR (exact skip test)
    unsigned smu;
    {
        unsigned b = mbits;
        #pragma unroll
        for (int off = 32; off >= 1; off >>= 1)
            b |= (unsigned)__shfl_xor((int)b, off, 64);
        smu = __builtin_amdgcn_readfirstlane(b);
    }

    f32x16 acc;
    #pragma unroll
    for (int r = 0; r < 16; ++r) acc[r] = 0.f;

    #pragma unroll
    for (int p = 0; p < 9; ++p) {
        const int pi = p / 3, pj = p - pi * 3;
        if (!((smu >> (3 * p)) & 7u)) continue;    // whole tap dead (scalar)

        // raw bf16 x fragments (lane-contiguous b128 LDS reads)
        B128 xr[2];   // [chalf]; plane s = chalf*2 + half
        const int cc2 = l + pj;
        #pragma unroll
        for (int ch = 0; ch < 2; ++ch)
            xr[ch].i4 = sx[((ch * 2 + half) * 3 + pi) * HW + cc2];

        #pragma unroll
        for (int t = 0; t < 3; ++t) {
            if ((smu >> (3 * p + t)) & 1u) {       // scalar branch
                unsigned m = 0u - ((mbits >> (3 * p + t)) & 1u);
                B128 a0, a1, b0, b1;
                a0.i4 = wA[(p * 6 + t * 2 + 0) * 128 + ot * 64 + lane];
                a1.i4 = wA[(p * 6 + t * 2 + 1) * 128 + ot * 64 + lane];
                b0.i4 = make_uint4(xr[0].i4.x & m, xr[0].i4.y & m,
                                   xr[0].i4.z & m, xr[0].i4.w & m);
                b1.i4 = make_uint4(xr[1].i4.x & m, xr[1].i4.y & m,
                                   xr[1].i4.z & m, xr[1].i4.w & m);
                acc = __builtin_amdgcn_mfma_f32_32x32x16_bf16(a0.v, b0.v, acc, 0, 0, 0);
                acc = __builtin_amdgcn_mfma_f32_32x32x16_bf16(a1.v, b1.v, acc, 0, 0, 0);
            }
        }
    }

    // epilogue: D[o_local = (reg&3)+8*(reg>>2)+4*half][col = l31] (proven)
    float* ob = out + (size_t)(n * OUT_C) * (IMG * IMG)
              + (size_t)row * IMG + colbase + ph * 32 + l31;
    #pragma unroll
    for (int reg = 0; reg < 16; ++reg) {
        int ol = (reg & 3) + 8 * (reg >> 2) + 4 * half + ot * 32;
        ob[(size_t)ol * (IMG * IMG)] = acc[reg];
    }
}

extern "C" void kernel_launch(void* const* d_in, const int* in_sizes, int n_in,
                              void* d_out, int out_size, void* d_ws, size_t ws_size,
                              hipStream_t stream) {
    const float* x        = (const float*)d_in[0];
    const float* disp     = (const float*)d_in[1];
    const float* fx       = (const float*)d_in[2];
    const float* baseline = (const float*)d_in[3];
    const float* w0       = (const float*)d_in[4];
    const float* w1       = (const float*)d_in[5];
    const float* w2       = (const float*)d_in[6];
    float* out            = (float*)d_out;

    __hip_bfloat16* wA = (__hip_bfloat16*)d_ws;   // 54*128*16 = 110592 B

    build_wA<<<27, 256, 0, stream>>>(w0, w1, w2, wA);
    conv25d_mfma6<<<2048, 256, 0, stream>>>(x, disp, fx, baseline,
                                            (const uint4*)wA, out);
}